// Round 6
// baseline (391.411 us; speedup 1.0000x reference)
//
#include <hip/hip_runtime.h>
#include <hip/hip_bf16.h>

typedef __bf16 bf16x8 __attribute__((ext_vector_type(8)));
typedef float  f32x4  __attribute__((ext_vector_type(4)));
typedef unsigned short u16;

// ---------- helpers ----------
static __device__ __forceinline__ u16 f2bf(float f) {
  union { float f; unsigned u; } v; v.f = f;
  unsigned r = v.u + 0x7fffu + ((v.u >> 16) & 1u);   // RNE
  return (u16)(r >> 16);
}

static __device__ __forceinline__ void gld16(const void* g, void* l) {
  __builtin_amdgcn_global_load_lds(
      (const __attribute__((address_space(1))) unsigned int*)g,
      (__attribute__((address_space(3))) unsigned int*)l, 16, 0, 0);
}

#define SBAR() do { __builtin_amdgcn_sched_barrier(0); \
                    __builtin_amdgcn_s_barrier(); \
                    __builtin_amdgcn_sched_barrier(0); } while (0)

// ---------- fused prep: 4 weight transposes (f32->bf16^T) + LN1 ----------
__global__ __launch_bounds__(256) void prep_k(
    const float* __restrict__ qkv_w, const float* __restrict__ proj_w,
    const float* __restrict__ fc1_w, const float* __restrict__ fc2_w,
    u16* __restrict__ wqkvT, u16* __restrict__ wprojT,
    u16* __restrict__ wfc1T, u16* __restrict__ wfc2T,
    const float* __restrict__ x, const float* __restrict__ g,
    const float* __restrict__ b, u16* __restrict__ hbuf) {
  const int bid = blockIdx.x;
  const int t = threadIdx.x;
  if (bid < 12288) {
    __shared__ float tile[32][33];
    const float* W; u16* Wt; int K, N, nx, i;
    if (bid < 3072)      { W = qkv_w;  Wt = wqkvT;  K = 1024; N = 3072; nx = 96;  i = bid; }
    else if (bid < 4096) { W = proj_w; Wt = wprojT; K = 1024; N = 1024; nx = 32;  i = bid - 3072; }
    else if (bid < 8192) { W = fc1_w;  Wt = wfc1T;  K = 1024; N = 4096; nx = 128; i = bid - 4096; }
    else                 { W = fc2_w;  Wt = wfc2T;  K = 4096; N = 1024; nx = 32;  i = bid - 8192; }
    const int n0 = (i % nx) * 32, k0 = (i / nx) * 32;
    const int r = t >> 3, c4 = (t & 7) * 4;
    const float4 v = *(const float4*)(W + (size_t)(k0 + r) * N + n0 + c4);
    tile[r][c4 + 0] = v.x; tile[r][c4 + 1] = v.y;
    tile[r][c4 + 2] = v.z; tile[r][c4 + 3] = v.w;
    __syncthreads();
    const int n = t >> 3, k4 = (t & 7) * 4;
    uint2 pk;
    pk.x = f2bf(tile[k4 + 0][n]) | ((unsigned)f2bf(tile[k4 + 1][n]) << 16);
    pk.y = f2bf(tile[k4 + 2][n]) | ((unsigned)f2bf(tile[k4 + 3][n]) << 16);
    *(uint2*)(Wt + (size_t)(n0 + n) * K + k0 + k4) = pk;
  } else {
    __shared__ float red[2][4];
    const size_t row = bid - 12288;
    const float4 v = *(const float4*)(x + row * 1024 + t * 4);
    float s = v.x + v.y + v.z + v.w;
    float ss = v.x * v.x + v.y * v.y + v.z * v.z + v.w * v.w;
    #pragma unroll
    for (int m = 1; m <= 32; m <<= 1) { s += __shfl_xor(s, m); ss += __shfl_xor(ss, m); }
    if ((t & 63) == 0) { red[0][t >> 6] = s; red[1][t >> 6] = ss; }
    __syncthreads();
    s  = red[0][0] + red[0][1] + red[0][2] + red[0][3];
    ss = red[1][0] + red[1][1] + red[1][2] + red[1][3];
    const float mu = s * (1.f / 1024.f);
    const float var = ss * (1.f / 1024.f) - mu * mu;
    const float rs = rsqrtf(var + 1e-5f);
    const float4 gv = *(const float4*)(g + t * 4);
    const float4 bv = *(const float4*)(b + t * 4);
    uint2 pk;
    pk.x = f2bf((v.x - mu) * rs * gv.x + bv.x) |
           ((unsigned)f2bf((v.y - mu) * rs * gv.y + bv.y) << 16);
    pk.y = f2bf((v.z - mu) * rs * gv.z + bv.z) |
           ((unsigned)f2bf((v.w - mu) * rs * gv.w + bv.w) << 16);
    *(uint2*)(hbuf + row * 1024 + t * 4) = pk;
  }
}

// ---------- layernorm f32 -> bf16 (row = 1024) ----------
__global__ __launch_bounds__(256) void ln_cast_k(
    const float* __restrict__ x, const float* __restrict__ g,
    const float* __restrict__ b, u16* __restrict__ out) {
  __shared__ float red[2][4];
  const int t = threadIdx.x;
  const size_t row = blockIdx.x;
  const float4 v = *(const float4*)(x + row * 1024 + t * 4);
  float s = v.x + v.y + v.z + v.w;
  float ss = v.x * v.x + v.y * v.y + v.z * v.z + v.w * v.w;
  #pragma unroll
  for (int m = 1; m <= 32; m <<= 1) { s += __shfl_xor(s, m); ss += __shfl_xor(ss, m); }
  if ((t & 63) == 0) { red[0][t >> 6] = s; red[1][t >> 6] = ss; }
  __syncthreads();
  s  = red[0][0] + red[0][1] + red[0][2] + red[0][3];
  ss = red[1][0] + red[1][1] + red[1][2] + red[1][3];
  const float mu = s * (1.f / 1024.f);
  const float var = ss * (1.f / 1024.f) - mu * mu;
  const float rs = rsqrtf(var + 1e-5f);
  const float4 gv = *(const float4*)(g + t * 4);
  const float4 bv = *(const float4*)(b + t * 4);
  uint2 pk;
  pk.x = f2bf((v.x - mu) * rs * gv.x + bv.x) |
         ((unsigned)f2bf((v.y - mu) * rs * gv.y + bv.y) << 16);
  pk.y = f2bf((v.z - mu) * rs * gv.z + bv.z) |
         ((unsigned)f2bf((v.w - mu) * rs * gv.w + bv.w) << 16);
  *(uint2*)(out + row * 1024 + t * 4) = pk;
}

// ---------- 16-wave GEMM (1024 thr, 4Mx4N waves of 64x64, BM=BN=256, BK=64) ----------
// EPI: 1 = tanh-GELU -> bf16; 3 = qkv -> bf16 + V^T extraction. LDS-restaged C.
// 2 phases/K-tile: ph0 {read B(all kk)+A kk0, stage A(T+1)->dn, bar, 16 MFMA, bar}
//                  ph1 {read A kk1, stage B(T+2)->d, bar, 16 MFMA, vmcnt(2), bar}
// B(d) fully consumed in ph0 (barrier-separated) so B(T+2)->d staging in ph1 is safe.
template <int EPI>
__global__ __launch_bounds__(1024, 1) void gemm16_k(
    const u16* __restrict__ A, const u16* __restrict__ Bt,
    const float* __restrict__ bias, u16* __restrict__ Cb,
    u16* __restrict__ vT, int M, int N, int K) {
  __shared__ u16 SH[65536];   // A: [d][16384], B: 32768 + [d][16384]; epi: C 256x256
  const int t = threadIdx.x;
  const int nt = N >> 8;
  const int q = gridDim.x >> 3;
  const int swz = (blockIdx.x & 7) * q + (blockIdx.x >> 3);
  const int tn = swz % nt, tm = swz / nt;
  const int lo = t & 15, hi = (t >> 4) & 3, wid = t >> 6;
  const int wm = wid >> 2, wn = wid & 3;
  const int NT = K >> 6;

  const int srow = t >> 3;                  // 0..127 within 128-row chunk
  const int sc = (t & 7) ^ (srow & 7);      // pre-swizzled 16B-chunk in source
  const u16* gA = A  + (size_t)(tm * 256) * K;
  const u16* gB = Bt + (size_t)(tn * 256) * K;
  auto stA = [&](int dd, int c, int T) {
    gld16(gA + (size_t)(c * 128 + srow) * K + (size_t)T * 64 + sc * 8,
          &SH[dd * 16384 + c * 8192 + t * 8]);
  };
  auto stB = [&](int dd, int c, int T) {
    gld16(gB + (size_t)(c * 128 + srow) * K + (size_t)T * 64 + sc * 8,
          &SH[32768 + dd * 16384 + c * 8192 + t * 8]);
  };

  const int xr = lo & 7;
  const int rowA = wm * 64 + lo;
  const int rowB = wn * 64 + lo;
#define RD_A(d, m, kk) (*(const bf16x8*)&SH[(d)*16384 + (rowA + (m)*16)*64 + ((((kk)<<2)+hi)^xr)*8])
#define RD_B(d, n, kk) (*(const bf16x8*)&SH[32768 + (d)*16384 + (rowB + (n)*16)*64 + ((((kk)<<2)+hi)^xr)*8])
#define MF(a, b, c) __builtin_amdgcn_mfma_f32_16x16x32_bf16(a, b, c, 0, 0, 0)

  f32x4 acc[4][4];
  #pragma unroll
  for (int i = 0; i < 4; ++i)
    #pragma unroll
    for (int j = 0; j < 4; ++j) acc[i][j] = (f32x4){0.f, 0.f, 0.f, 0.f};

  // prologue: A0, B0 (buf0) + B1 (buf1); drain buf0, keep B1 in flight
  stA(0, 0, 0); stA(0, 1, 0); stB(0, 0, 0); stB(0, 1, 0);
  stB(1, 0, 1); stB(1, 1, 1);
  asm volatile("s_waitcnt vmcnt(2)" ::: "memory");
  SBAR();

  for (int T = 0; T < NT; ++T) {
    const int d = T & 1, dn = d ^ 1;
    // ---- ph0: all B (both kk) + A kk0 ; stage A(T+1) -> dn
    bf16x8 b00 = RD_B(d,0,0), b01 = RD_B(d,0,1), b10 = RD_B(d,1,0), b11 = RD_B(d,1,1);
    bf16x8 b20 = RD_B(d,2,0), b21 = RD_B(d,2,1), b30 = RD_B(d,3,0), b31 = RD_B(d,3,1);
    {
      bf16x8 a0 = RD_A(d,0,0), a1 = RD_A(d,1,0), a2 = RD_A(d,2,0), a3 = RD_A(d,3,0);
      if (T + 1 < NT) { stA(dn, 0, T + 1); stA(dn, 1, T + 1); }
      SBAR();
      __builtin_amdgcn_s_setprio(1);
      acc[0][0]=MF(a0,b00,acc[0][0]); acc[0][1]=MF(a0,b10,acc[0][1]);
      acc[0][2]=MF(a0,b20,acc[0][2]); acc[0][3]=MF(a0,b30,acc[0][3]);
      acc[1][0]=MF(a1,b00,acc[1][0]); acc[1][1]=MF(a1,b10,acc[1][1]);
      acc[1][2]=MF(a1,b20,acc[1][2]); acc[1][3]=MF(a1,b30,acc[1][3]);
      acc[2][0]=MF(a2,b00,acc[2][0]); acc[2][1]=MF(a2,b10,acc[2][1]);
      acc[2][2]=MF(a2,b20,acc[2][2]); acc[2][3]=MF(a2,b30,acc[2][3]);
      acc[3][0]=MF(a3,b00,acc[3][0]); acc[3][1]=MF(a3,b10,acc[3][1]);
      acc[3][2]=MF(a3,b20,acc[3][2]); acc[3][3]=MF(a3,b30,acc[3][3]);
      __builtin_amdgcn_s_setprio(0);
      SBAR();
    }
    // ---- ph1: A kk1 ; stage B(T+2) -> d (B(d) consumed in ph0)
    {
      bf16x8 a0 = RD_A(d,0,1), a1 = RD_A(d,1,1), a2 = RD_A(d,2,1), a3 = RD_A(d,3,1);
      if (T + 2 < NT) { stB(d, 0, T + 2); stB(d, 1, T + 2); }
      SBAR();
      __builtin_amdgcn_s_setprio(1);
      acc[0][0]=MF(a0,b01,acc[0][0]); acc[0][1]=MF(a0,b11,acc[0][1]);
      acc[0][2]=MF(a0,b21,acc[0][2]); acc[0][3]=MF(a0,b31,acc[0][3]);
      acc[1][0]=MF(a1,b01,acc[1][0]); acc[1][1]=MF(a1,b11,acc[1][1]);
      acc[1][2]=MF(a1,b21,acc[1][2]); acc[1][3]=MF(a1,b31,acc[1][3]);
      acc[2][0]=MF(a2,b01,acc[2][0]); acc[2][1]=MF(a2,b11,acc[2][1]);
      acc[2][2]=MF(a2,b21,acc[2][2]); acc[2][3]=MF(a2,b31,acc[2][3]);
      acc[3][0]=MF(a3,b01,acc[3][0]); acc[3][1]=MF(a3,b11,acc[3][1]);
      acc[3][2]=MF(a3,b21,acc[3][2]); acc[3][3]=MF(a3,b31,acc[3][3]);
      __builtin_amdgcn_s_setprio(0);
      if (T < NT - 2)       { asm volatile("s_waitcnt vmcnt(2)" ::: "memory"); }
      else if (T == NT - 2) { asm volatile("s_waitcnt vmcnt(0)" ::: "memory"); }
      SBAR();
    }
  }

  // ---- epilogue: restage C (bf16) through LDS, coalesced dwordx4 stores ----
  #pragma unroll
  for (int ni = 0; ni < 4; ++ni) {
    const int colL = wn * 64 + ni * 16 + lo;
    const float bv = bias[tn * 256 + colL];
    #pragma unroll
    for (int mi = 0; mi < 4; ++mi) {
      const int rowL = wm * 64 + mi * 16 + hi * 4;
      #pragma unroll
      for (int r = 0; r < 4; ++r) {
        float val = acc[mi][ni][r] + bv;
        if (EPI == 1) {
          const float u = 0.79788456f * val * (1.f + 0.044715f * val * val);
          const float e = __expf(fminf(2.f * u, 80.f));
          val = val * (e / (e + 1.f));
        }
        SH[(rowL + r) * 256 + colL] = f2bf(val);
      }
    }
  }
  __syncthreads();
  {
    const int base = t * 16;
    #pragma unroll
    for (int p = 0; p < 8; ++p) {
      const int o = base + p * 16384;            // byte offset in 128 KB tile
      const int row = o >> 9;
      const int cb = (o & 511) >> 1;             // col (u16)
      const uint4 v4 = *(const uint4*)&SH[o >> 1];
      *(uint4*)(Cb + (size_t)(tm * 256 + row) * N + tn * 256 + cb) = v4;
    }
  }
  if constexpr (EPI == 3) {
    if (tn >= 8) {                               // V columns (global col >= 2048)
      const int c = t & 255;
      const int rg = t >> 8;                     // 0..3 row-quarter (64 rows)
      const int gcol = tn * 256 + c;
      const int hh = (gcol - 2048) >> 6, dd = gcol & 63;
      const int bb = tm >> 2, nb = (tm & 3) * 256;
      u16* dst = vT + ((size_t)((bb * 16 + hh) * 64 + dd) << 10) + nb + rg * 64;
      #pragma unroll
      for (int i = 0; i < 8; ++i) {
        const int r0 = rg * 64 + i * 8;
        u16 tv[8];
        #pragma unroll
        for (int j = 0; j < 8; ++j) tv[j] = SH[(r0 + j) * 256 + c];
        uint4 pk;
        pk.x = tv[0] | ((unsigned)tv[1] << 16);
        pk.y = tv[2] | ((unsigned)tv[3] << 16);
        pk.z = tv[4] | ((unsigned)tv[5] << 16);
        pk.w = tv[6] | ((unsigned)tv[7] << 16);
        *(uint4*)(dst + i * 8) = pk;
      }
    }
  }
#undef RD_A
#undef RD_B
#undef MF
}

// ---------- 8-wave GEMM (512 thr, BM=256 BN=128), EPI = +resid -> f32 ----------
__global__ __launch_bounds__(512, 2) void gemmP_k(
    const u16* __restrict__ A, const u16* __restrict__ Bt,
    const float* __restrict__ bias, float* __restrict__ Cf,
    const float* __restrict__ R, int M, int N, int K) {
  __shared__ u16 SH[49152];   // A: [d][16384] (256x64 x2), B: 32768 + [d][8192] (128x64 x2)
  const int t = threadIdx.x;
  const int nt = N >> 7;
  const int q = gridDim.x >> 3;
  const int swz = (blockIdx.x & 7) * q + (blockIdx.x >> 3);
  const int tn = swz % nt, tm = swz / nt;
  const int lo = t & 15, hi = (t >> 4) & 3, wid = t >> 6;
  const int wm = wid >> 1, wn = wid & 1;
  const int NT = K >> 6;

  const int srow = t >> 3;
  const int sc = (t & 7) ^ (srow & 7);
  const u16* gA = A  + (size_t)(tm * 256) * K;
  const u16* gB = Bt + (size_t)(tn * 128) * K;
  auto stA = [&](int dd, int c, int T) {
    gld16(gA + (size_t)(c * 64 + srow) * K + (size_t)T * 64 + sc * 8,
          &SH[dd * 16384 + c * 4096 + t * 8]);
  };
  auto stB = [&](int dd, int c, int T) {
    gld16(gB + (size_t)(c * 64 + srow) * K + (size_t)T * 64 + sc * 8,
          &SH[32768 + dd * 8192 + c * 4096 + t * 8]);
  };

  const int xr = lo & 7;
  const int rowA = wm * 64 + lo;
  const int rowB = wn * 64 + lo;
#define RD_A(d, m, kk) (*(const bf16x8*)&SH[(d)*16384 + (rowA + (m)*16)*64 + ((((kk)<<2)+hi)^xr)*8])
#define RD_B(d, n, kk) (*(const bf16x8*)&SH[32768 + (d)*8192 + (rowB + (n)*16)*64 + ((((kk)<<2)+hi)^xr)*8])
#define MF(a, b, c) __builtin_amdgcn_mfma_f32_16x16x32_bf16(a, b, c, 0, 0, 0)

  f32x4 acc[4][4];
  #pragma unroll
  for (int i = 0; i < 4; ++i)
    #pragma unroll
    for (int j = 0; j < 4; ++j) acc[i][j] = (f32x4){0.f, 0.f, 0.f, 0.f};

#define PH8(d, M0, STAGES, WAITS) do { \
    bf16x8 a0 = RD_A(d, M0, 0), a1 = RD_A(d, M0, 1); \
    STAGES; SBAR(); __builtin_amdgcn_s_setprio(1); \
    acc[M0][0]=MF(a0,b00,acc[M0][0]); acc[M0][1]=MF(a0,b10,acc[M0][1]); \
    acc[M0][2]=MF(a0,b20,acc[M0][2]); acc[M0][3]=MF(a0,b30,acc[M0][3]); \
    acc[M0][0]=MF(a1,b01,acc[M0][0]); acc[M0][1]=MF(a1,b11,acc[M0][1]); \
    acc[M0][2]=MF(a1,b21,acc[M0][2]); acc[M0][3]=MF(a1,b31,acc[M0][3]); \
    __builtin_amdgcn_s_setprio(0); WAITS; SBAR(); } while (0)

  stA(0, 0, 0); stA(0, 1, 0); stA(0, 2, 0); stA(0, 3, 0);
  stB(0, 0, 0); stB(0, 1, 0);
  stB(1, 0, 1); stB(1, 1, 1);
  asm volatile("s_waitcnt vmcnt(2)" ::: "memory");
  SBAR();
  for (int T = 0; T < NT; ++T) {
    const int d = T & 1, dn = d ^ 1;
    bf16x8 b00 = RD_B(d,0,0), b01 = RD_B(d,0,1), b10 = RD_B(d,1,0), b11 = RD_B(d,1,1);
    bf16x8 b20 = RD_B(d,2,0), b21 = RD_B(d,2,1), b30 = RD_B(d,3,0), b31 = RD_B(d,3,1);
    PH8(d, 0, { if (T + 1 < NT) { stA(dn, 0, T + 1); stA(dn, 1, T + 1);
                                  stA(dn, 2, T + 1); stA(dn, 3, T + 1); } }, );
    PH8(d, 1, { if (T + 2 < NT) { stB(d, 0, T + 2); stB(d, 1, T + 2); } }, );
    PH8(d, 2, , );
    PH8(d, 3, ,
        { if (T < NT - 2)       { asm volatile("s_waitcnt vmcnt(2)" ::: "memory"); }
          else if (T == NT - 2) { asm volatile("s_waitcnt vmcnt(0)" ::: "memory"); } });
  }

  #pragma unroll
  for (int ni = 0; ni < 4; ++ni) {
    const int col = tn * 128 + wn * 64 + ni * 16 + lo;
    const float bv = bias[col];
    #pragma unroll
    for (int mi = 0; mi < 4; ++mi) {
      const int row0 = tm * 256 + wm * 64 + mi * 16 + hi * 4;
      #pragma unroll
      for (int r = 0; r < 4; ++r) {
        const size_t idx = (size_t)(row0 + r) * N + col;
        Cf[idx] = acc[mi][ni][r] + bv + R[idx];
      }
    }
  }
#undef RD_A
#undef RD_B
#undef MF
#undef PH8
}

// ---------- flash attention: S^T = K@Q^T (swapped), online softmax, O = P@V ----------
__global__ __launch_bounds__(256, 2) void attn_k(
    const u16* __restrict__ qkv, const u16* __restrict__ vT, u16* __restrict__ o) {
  __shared__ u16 lK[64 * 64];
  __shared__ u16 lV[64 * 64];
  __shared__ u16 lP[64 * 72];
  const int t = threadIdx.x;
  const int lo = t & 15, hi = (t >> 4) & 3, w = t >> 6;
  const int swz = (blockIdx.x & 7) * 256 + (blockIdx.x >> 3);
  const int qt = swz & 15, bh = swz >> 4;
  const int b = bh >> 4, h = bh & 15;
  const int q0 = qt * 64;
  const u16* Qb = qkv + (size_t)b * 1024 * 3072 + h * 64;
  const u16* Kb = Qb + 1024;
  const u16* Vt = vT + (size_t)bh * 64 * 1024;

  bf16x8 qf[2];
  {
    const size_t q = q0 + w * 16 + lo;
    qf[0] = *(const bf16x8*)(Qb + q * 3072 + hi * 8);
    qf[1] = *(const bf16x8*)(Qb + q * 3072 + 32 + hi * 8);
  }
  f32x4 oacc[4];
  #pragma unroll
  for (int i = 0; i < 4; ++i) oacc[i] = (f32x4){0.f, 0.f, 0.f, 0.f};
  float m = -1e30f, lsum = 0.f;
  const int srow = t >> 3;
  const int sc = (t & 7) ^ (srow & 7);
  const int xr = lo & 7;
  const float SC = 0.125f * 1.44269504f;

  for (int kv0 = 0; kv0 < 1024; kv0 += 64) {
    __syncthreads();
    #pragma unroll
    for (int j = 0; j < 2; ++j) {
      const int r64 = j * 32 + srow;
      gld16(Kb + (size_t)(kv0 + r64) * 3072 + sc * 8, &lK[(j * 256 + t) * 8]);
      gld16(Vt + (size_t)r64 * 1024 + kv0 + sc * 8, &lV[(j * 256 + t) * 8]);
    }
    __syncthreads();

    f32x4 s[4];
    #pragma unroll
    for (int i = 0; i < 4; ++i) s[i] = (f32x4){0.f, 0.f, 0.f, 0.f};
    #pragma unroll
    for (int kk = 0; kk < 2; ++kk) {
      #pragma unroll
      for (int mi = 0; mi < 4; ++mi) {
        const bf16x8 kf = *(const bf16x8*)&lK[(mi * 16 + lo) * 64 + (((kk << 2) + hi) ^ xr) * 8];
        s[mi] = __builtin_amdgcn_mfma_f32_16x16x32_bf16(kf, qf[kk], s[mi], 0, 0, 0);
      }
    }
    float sv[16];
    float tmax = -1e30f;
    #pragma unroll
    for (int mi = 0; mi < 4; ++mi)
      #pragma unroll
      for (int r = 0; r < 4; ++r) {
        const float xx = s[mi][r] * SC;
        sv[mi * 4 + r] = xx;
        tmax = fmaxf(tmax, xx);
      }
    tmax = fmaxf(tmax, __shfl_xor(tmax, 16));
    tmax = fmaxf(tmax, __shfl_xor(tmax, 32));
    if (__any(tmax > m + 11.5f)) {
      const float mnew = fmaxf(m, tmax);
      const float alpha = exp2f(m - mnew);
      m = mnew;
      lsum *= alpha;
      float ar[4];
      #pragma unroll
      for (int r = 0; r < 4; ++r) ar[r] = __shfl(alpha, hi * 4 + r);
      #pragma unroll
      for (int ni = 0; ni < 4; ++ni)
        #pragma unroll
        for (int r = 0; r < 4; ++r) oacc[ni][r] *= ar[r];
    }
    float p[16], ts = 0.f;
    #pragma unroll
    for (int i = 0; i < 16; ++i) { p[i] = exp2f(sv[i] - m); ts += p[i]; }
    ts += __shfl_xor(ts, 16);
    ts += __shfl_xor(ts, 32);
    lsum += ts;
    #pragma unroll
    for (int mi = 0; mi < 4; ++mi) {
      uint2 pk;
      pk.x = f2bf(p[mi * 4 + 0]) | ((unsigned)f2bf(p[mi * 4 + 1]) << 16);
      pk.y = f2bf(p[mi * 4 + 2]) | ((unsigned)f2bf(p[mi * 4 + 3]) << 16);
      *(uint2*)&lP[(w * 16 + lo) * 72 + mi * 16 + hi * 4] = pk;
    }
    asm volatile("s_waitcnt lgkmcnt(0)" ::: "memory");
    #pragma unroll
    for (int kk = 0; kk < 2; ++kk) {
      const bf16x8 pf = *(const bf16x8*)&lP[(w * 16 + lo) * 72 + kk * 32 + hi * 8];
      #pragma unroll
      for (int ni = 0; ni < 4; ++ni) {
        const bf16x8 vf = *(const bf16x8*)&lV[(ni * 16 + lo) * 64 + (((kk << 2) + hi) ^ xr) * 8];
        oacc[ni] = __builtin_amdgcn_mfma_f32_16x16x32_bf16(pf, vf, oacc[ni], 0, 0, 0);
      }
    }
  }
  float lr[4];
  #pragma unroll
  for (int r = 0; r < 4; ++r) lr[r] = 1.f / __shfl(lsum, hi * 4 + r);
  #pragma unroll
  for (int ni = 0; ni < 4; ++ni) {
    const int d = ni * 16 + lo;
    #pragma unroll
    for (int r = 0; r < 4; ++r) {
      const int n = q0 + w * 16 + hi * 4 + r;
      o[((size_t)(b * 1024 + n) * 16 + h) * 64 + d] = f2bf(oacc[ni][r] * lr[r]);
    }
  }
}

// ---------- launch ----------
extern "C" void kernel_launch(void* const* d_in, const int* in_sizes, int n_in,
                              void* d_out, int out_size, void* d_ws, size_t ws_size,
                              hipStream_t stream) {
  const float* x      = (const float*)d_in[0];
  const float* qkv_w  = (const float*)d_in[1];
  const float* qkv_b  = (const float*)d_in[2];
  const float* proj_w = (const float*)d_in[3];
  const float* proj_b = (const float*)d_in[4];
  const float* fc1_w  = (const float*)d_in[5];
  const float* fc1_b  = (const float*)d_in[6];
  const float* fc2_w  = (const float*)d_in[7];
  const float* fc2_b  = (const float*)d_in[8];
  const float* ln1_g  = (const float*)d_in[9];
  const float* ln1_b  = (const float*)d_in[10];
  const float* ln2_g  = (const float*)d_in[11];
  const float* ln2_b  = (const float*)d_in[12];
  float* out = (float*)d_out;
  char* ws = (char*)d_ws;
  u16* wqkvT = (u16*)(ws);              // [3072][1024]  6,291,456
  u16* wprojT = (u16*)(ws + 6291456);   // [1024][1024]  2,097,152
  u16* wfc1T = (u16*)(ws + 8388608);    // [4096][1024]  8,388,608
  u16* wfc2T = (u16*)(ws + 16777216);   // [1024][4096]  8,388,608
  u16* hbuf  = (u16*)(ws + 25165824);   // [8192][1024] 16,777,216
  u16* qkvo  = (u16*)(ws + 41943040);   // [8192][3072] 50,331,648
  u16* vT    = (u16*)(ws + 92274688);   // [128][64][1024] 16,777,216
  u16* fc1o  = qkvo;                    // [8192][4096] overlays qkv+vT (both dead)

  prep_k<<<20480, 256, 0, stream>>>(qkv_w, proj_w, fc1_w, fc2_w,
                                    wqkvT, wprojT, wfc1T, wfc2T,
                                    x, ln1_g, ln1_b, hbuf);
  gemm16_k<3><<<384, 1024, 0, stream>>>(hbuf, wqkvT, qkv_b, qkvo, vT, 8192, 3072, 1024);
  attn_k<<<2048, 256, 0, stream>>>(qkvo, vT, hbuf);
  gemmP_k<<<256, 512, 0, stream>>>(hbuf, wprojT, proj_b, out, x, 8192, 1024, 1024);
  ln_cast_k<<<8192, 256, 0, stream>>>(out, ln2_g, ln2_b, hbuf);
  gemm16_k<1><<<512, 1024, 0, stream>>>(hbuf, wfc1T, fc1_b, fc1o, nullptr, 8192, 4096, 1024);
  gemmP_k<<<256, 512, 0, stream>>>(fc1o, wfc2T, fc2_b, out, out, 8192, 1024, 4096);
}

// Round 9
// 374.302 us; speedup vs baseline: 1.0457x; 1.0457x over previous
//
#include <hip/hip_runtime.h>
#include <hip/hip_bf16.h>

typedef __bf16 bf16x8 __attribute__((ext_vector_type(8)));
typedef float  f32x4  __attribute__((ext_vector_type(4)));
typedef unsigned short u16;

// ---------- helpers ----------
static __device__ __forceinline__ u16 f2bf(float f) {
  union { float f; unsigned u; } v; v.f = f;
  unsigned r = v.u + 0x7fffu + ((v.u >> 16) & 1u);   // RNE
  return (u16)(r >> 16);
}

static __device__ __forceinline__ void gld16(const void* g, void* l) {
  __builtin_amdgcn_global_load_lds(
      (const __attribute__((address_space(1))) unsigned int*)g,
      (__attribute__((address_space(3))) unsigned int*)l, 16, 0, 0);
}

#define SBAR() do { __builtin_amdgcn_sched_barrier(0); \
                    __builtin_amdgcn_s_barrier(); \
                    __builtin_amdgcn_sched_barrier(0); } while (0)

// ---------- fused prep: 4 weight transposes (f32->bf16^T) + LN1 ----------
__global__ __launch_bounds__(256) void prep_k(
    const float* __restrict__ qkv_w, const float* __restrict__ proj_w,
    const float* __restrict__ fc1_w, const float* __restrict__ fc2_w,
    u16* __restrict__ wqkvT, u16* __restrict__ wprojT,
    u16* __restrict__ wfc1T, u16* __restrict__ wfc2T,
    const float* __restrict__ x, const float* __restrict__ g,
    const float* __restrict__ b, u16* __restrict__ hbuf) {
  const int bid = blockIdx.x;
  const int t = threadIdx.x;
  if (bid < 12288) {
    __shared__ float tile[32][33];
    const float* W; u16* Wt; int K, N, nx, i;
    if (bid < 3072)      { W = qkv_w;  Wt = wqkvT;  K = 1024; N = 3072; nx = 96;  i = bid; }
    else if (bid < 4096) { W = proj_w; Wt = wprojT; K = 1024; N = 1024; nx = 32;  i = bid - 3072; }
    else if (bid < 8192) { W = fc1_w;  Wt = wfc1T;  K = 1024; N = 4096; nx = 128; i = bid - 4096; }
    else                 { W = fc2_w;  Wt = wfc2T;  K = 4096; N = 1024; nx = 32;  i = bid - 8192; }
    const int n0 = (i % nx) * 32, k0 = (i / nx) * 32;
    const int r = t >> 3, c4 = (t & 7) * 4;
    const float4 v = *(const float4*)(W + (size_t)(k0 + r) * N + n0 + c4);
    tile[r][c4 + 0] = v.x; tile[r][c4 + 1] = v.y;
    tile[r][c4 + 2] = v.z; tile[r][c4 + 3] = v.w;
    __syncthreads();
    const int n = t >> 3, k4 = (t & 7) * 4;
    uint2 pk;
    pk.x = f2bf(tile[k4 + 0][n]) | ((unsigned)f2bf(tile[k4 + 1][n]) << 16);
    pk.y = f2bf(tile[k4 + 2][n]) | ((unsigned)f2bf(tile[k4 + 3][n]) << 16);
    *(uint2*)(Wt + (size_t)(n0 + n) * K + k0 + k4) = pk;
  } else {
    __shared__ float red[2][4];
    const size_t row = bid - 12288;
    const float4 v = *(const float4*)(x + row * 1024 + t * 4);
    float s = v.x + v.y + v.z + v.w;
    float ss = v.x * v.x + v.y * v.y + v.z * v.z + v.w * v.w;
    #pragma unroll
    for (int m = 1; m <= 32; m <<= 1) { s += __shfl_xor(s, m); ss += __shfl_xor(ss, m); }
    if ((t & 63) == 0) { red[0][t >> 6] = s; red[1][t >> 6] = ss; }
    __syncthreads();
    s  = red[0][0] + red[0][1] + red[0][2] + red[0][3];
    ss = red[1][0] + red[1][1] + red[1][2] + red[1][3];
    const float mu = s * (1.f / 1024.f);
    const float var = ss * (1.f / 1024.f) - mu * mu;
    const float rs = rsqrtf(var + 1e-5f);
    const float4 gv = *(const float4*)(g + t * 4);
    const float4 bv = *(const float4*)(b + t * 4);
    uint2 pk;
    pk.x = f2bf((v.x - mu) * rs * gv.x + bv.x) |
           ((unsigned)f2bf((v.y - mu) * rs * gv.y + bv.y) << 16);
    pk.y = f2bf((v.z - mu) * rs * gv.z + bv.z) |
           ((unsigned)f2bf((v.w - mu) * rs * gv.w + bv.w) << 16);
    *(uint2*)(hbuf + row * 1024 + t * 4) = pk;
  }
}

// ---------- layernorm f32 -> bf16 (row = 1024) ----------
__global__ __launch_bounds__(256) void ln_cast_k(
    const float* __restrict__ x, const float* __restrict__ g,
    const float* __restrict__ b, u16* __restrict__ out) {
  __shared__ float red[2][4];
  const int t = threadIdx.x;
  const size_t row = blockIdx.x;
  const float4 v = *(const float4*)(x + row * 1024 + t * 4);
  float s = v.x + v.y + v.z + v.w;
  float ss = v.x * v.x + v.y * v.y + v.z * v.z + v.w * v.w;
  #pragma unroll
  for (int m = 1; m <= 32; m <<= 1) { s += __shfl_xor(s, m); ss += __shfl_xor(ss, m); }
  if ((t & 63) == 0) { red[0][t >> 6] = s; red[1][t >> 6] = ss; }
  __syncthreads();
  s  = red[0][0] + red[0][1] + red[0][2] + red[0][3];
  ss = red[1][0] + red[1][1] + red[1][2] + red[1][3];
  const float mu = s * (1.f / 1024.f);
  const float var = ss * (1.f / 1024.f) - mu * mu;
  const float rs = rsqrtf(var + 1e-5f);
  const float4 gv = *(const float4*)(g + t * 4);
  const float4 bv = *(const float4*)(b + t * 4);
  uint2 pk;
  pk.x = f2bf((v.x - mu) * rs * gv.x + bv.x) |
         ((unsigned)f2bf((v.y - mu) * rs * gv.y + bv.y) << 16);
  pk.y = f2bf((v.z - mu) * rs * gv.z + bv.z) |
         ((unsigned)f2bf((v.w - mu) * rs * gv.w + bv.w) << 16);
  *(uint2*)(out + row * 1024 + t * 4) = pk;
}

// ---------- single-barrier pipelined GEMM: C = A @ Bt^T + bias ----------
// 512 thr = 8 waves. WN=4: waves 2m x 4n, per-wave 128x64. WN=2: 4m x 2n, 64x64.
// Per K-tile: LDA phase-0 (post-barrier, buffer d complete); stage T+1 -> dn;
// B-frags held whole tile; A-frags ping-pong one phase ahead; 4 MFMA bursts,
// NO internal barriers; vmcnt(0) + ONE s_barrier per tile.
// RACE NOTE: all reads of a buffer occur between the barrier that publishes it
// and the barrier that ends the tile; no pre-barrier cross-wave reads.
// EPI: 1 = tanh-GELU -> bf16 (LDS-restaged); 2 = +resid -> f32 (direct);
//      3 = qkv -> bf16 + V^T extraction (LDS-restaged)
template <int EPI, int WN>
__global__ __launch_bounds__(512, 1) void gemm_k(
    const u16* __restrict__ A, const u16* __restrict__ Bt,
    const float* __restrict__ bias, u16* __restrict__ Cb, float* __restrict__ Cf,
    const float* __restrict__ R, u16* __restrict__ vT, int M, int N, int K) {
  constexpr int MR = 2 * WN;          // m-reps per wave
  constexpr int MPP = MR / 4;         // m-reps per phase
  constexpr int BN = 64 * WN;
  __shared__ u16 SH[32768 + WN * 8192];   // A dbuf | B dbuf; epilogue: C tile
  const int t = threadIdx.x;
  const int nt = N / BN;
  const int q = gridDim.x >> 3;       // grid divisible by 8
  const int swz = (blockIdx.x & 7) * q + (blockIdx.x >> 3);
  const int tn = swz % nt, tm = swz / nt;
  const int lo = t & 15, hi = (t >> 4) & 3, wid = t >> 6;
  const int wm = wid / WN, wn = wid & (WN - 1);
  const int NT = K >> 6;

  const int srow = t >> 3;                  // 0..63 within 64-row chunk
  const int sc = (t & 7) ^ (srow & 7);      // pre-swizzled 16B-chunk in source
  const u16* gA = A  + (size_t)(tm * 256) * K;
  const u16* gB = Bt + (size_t)(tn * BN) * K;
  auto STAGE = [&](int dd, int T) {
    #pragma unroll
    for (int c = 0; c < 4; ++c)
      gld16(gA + (size_t)(c * 64 + srow) * K + (size_t)T * 64 + sc * 8,
            &SH[dd * 16384 + c * 4096 + t * 8]);
    #pragma unroll
    for (int c = 0; c < WN; ++c)
      gld16(gB + (size_t)(c * 64 + srow) * K + (size_t)T * 64 + sc * 8,
            &SH[32768 + dd * (WN * 4096) + c * 4096 + t * 8]);
  };

  const int xr = lo & 7;
  const int rowA = wm * (MR * 16) + lo;
  const int rowB = wn * 64 + lo;
#define RD_A(d, m, kk) (*(const bf16x8*)&SH[(d)*16384 + (rowA + (m)*16)*64 + ((((kk)<<2)+hi)^xr)*8])
#define RD_B(d, n, kk) (*(const bf16x8*)&SH[32768 + (d)*(WN*4096) + (rowB + (n)*16)*64 + ((((kk)<<2)+hi)^xr)*8])
#define MF(a, b, c) __builtin_amdgcn_mfma_f32_16x16x32_bf16(a, b, c, 0, 0, 0)

  f32x4 acc[MR][4];
  #pragma unroll
  for (int i = 0; i < MR; ++i)
    #pragma unroll
    for (int j = 0; j < 4; ++j) acc[i][j] = (f32x4){0.f, 0.f, 0.f, 0.f};

  bf16x8 bF[8];                       // n*2+kk, held whole K-tile
  bf16x8 aP[MPP * 2], aQ[MPP * 2];    // ping-pong phase frags: ml*2+kk

  auto LDA = [&](bf16x8* arr, int d, int p) {
    #pragma unroll
    for (int ml = 0; ml < MPP; ++ml) {
      arr[ml * 2 + 0] = RD_A(d, p * MPP + ml, 0);
      arr[ml * 2 + 1] = RD_A(d, p * MPP + ml, 1);
    }
  };
  auto LDB = [&](int d) {
    #pragma unroll
    for (int n = 0; n < 4; ++n) {
      bF[n * 2 + 0] = RD_B(d, n, 0);
      bF[n * 2 + 1] = RD_B(d, n, 1);
    }
  };
  auto DOMF = [&](bf16x8* arr, int p) {
    __builtin_amdgcn_s_setprio(1);
    #pragma unroll
    for (int kk = 0; kk < 2; ++kk)
      #pragma unroll
      for (int ml = 0; ml < MPP; ++ml) {
        const int m = p * MPP + ml;
        #pragma unroll
        for (int n = 0; n < 4; ++n)
          acc[m][n] = MF(arr[ml * 2 + kk], bF[n * 2 + kk], acc[m][n]);
      }
    __builtin_amdgcn_s_setprio(0);
  };

  // prologue: stage tile0, drain own stores, barrier publishes buffer 0
  STAGE(0, 0);
  asm volatile("s_waitcnt vmcnt(0)" ::: "memory");
  SBAR();

  for (int T = 0; T < NT; ++T) {
    const int d = T & 1, dn = d ^ 1;
    LDA(aP, d, 0);                    // post-barrier: buffer d fully published
    if (T + 1 < NT) STAGE(dn, T + 1);
    LDB(d);
    LDA(aQ, d, 1);
    DOMF(aP, 0);
    LDA(aP, d, 2);
    DOMF(aQ, 1);
    LDA(aQ, d, 3);
    DOMF(aP, 2);
    DOMF(aQ, 3);
    if (T + 1 < NT) { asm volatile("s_waitcnt vmcnt(0)" ::: "memory"); }
    SBAR();
  }

  // ---- epilogue ----
  if constexpr (EPI == 2) {
    #pragma unroll
    for (int ni = 0; ni < 4; ++ni) {
      const int col = tn * BN + wn * 64 + ni * 16 + lo;
      const float bv = bias[col];
      #pragma unroll
      for (int mi = 0; mi < MR; ++mi) {
        const int row0 = tm * 256 + wm * (MR * 16) + mi * 16 + hi * 4;
        #pragma unroll
        for (int r = 0; r < 4; ++r) {
          const size_t idx = (size_t)(row0 + r) * N + col;
          Cf[idx] = acc[mi][ni][r] + bv + R[idx];
        }
      }
    }
  } else {
    // restage C tile (bf16) through LDS, coalesced dwordx4 stores
    #pragma unroll
    for (int ni = 0; ni < 4; ++ni) {
      const int colL = wn * 64 + ni * 16 + lo;
      const float bv = bias[tn * BN + colL];
      #pragma unroll
      for (int mi = 0; mi < MR; ++mi) {
        const int rowL = wm * (MR * 16) + mi * 16 + hi * 4;
        #pragma unroll
        for (int r = 0; r < 4; ++r) {
          float val = acc[mi][ni][r] + bv;
          if (EPI == 1) {
            const float u = 0.79788456f * val * (1.f + 0.044715f * val * val);
            const float e = __expf(fminf(2.f * u, 80.f));
            val = val * (e / (e + 1.f));
          }
          SH[(rowL + r) * BN + colL] = f2bf(val);
        }
      }
    }
    __syncthreads();
    constexpr int ROWSH = (BN == 256) ? 9 : 8;   // log2(BN*2)
    const int base = t * 16;
    #pragma unroll
    for (int p = 0; p < BN / 16; ++p) {
      const int o = base + p * 8192;             // byte offset in tile
      const int row = o >> ROWSH;
      const int cb = (o & (2 * BN - 1)) >> 1;    // col (u16)
      const uint4 v4 = *(const uint4*)&SH[o >> 1];
      *(uint4*)(Cb + (size_t)(tm * 256 + row) * N + tn * BN + cb) = v4;
    }
    if constexpr (EPI == 3) {
      if (tn >= 8) {                             // V columns (global col >= 2048)
        const int c = t & 255;
        const int rg = t >> 8;                   // 0..1 row-half
        const int gcol = tn * 256 + c;
        const int hh = (gcol - 2048) >> 6, dd = gcol & 63;
        const int bb = tm >> 2, nb = (tm & 3) * 256;
        u16* dst = vT + ((size_t)((bb * 16 + hh) * 64 + dd) << 10) + nb + rg * 128;
        #pragma unroll
        for (int i = 0; i < 16; ++i) {
          const int r0 = rg * 128 + i * 8;
          u16 tv[8];
          #pragma unroll
          for (int j = 0; j < 8; ++j) tv[j] = SH[(r0 + j) * 256 + c];
          uint4 pk;
          pk.x = tv[0] | ((unsigned)tv[1] << 16);
          pk.y = tv[2] | ((unsigned)tv[3] << 16);
          pk.z = tv[4] | ((unsigned)tv[5] << 16);
          pk.w = tv[6] | ((unsigned)tv[7] << 16);
          *(uint4*)(dst + i * 8) = pk;
        }
      }
    }
  }
#undef RD_A
#undef RD_B
#undef MF
}

// ---------- flash attention: S^T = K@Q^T (swapped), online softmax, O = P@V ----------
__global__ __launch_bounds__(256, 2) void attn_k(
    const u16* __restrict__ qkv, const u16* __restrict__ vT, u16* __restrict__ o) {
  __shared__ u16 lK[64 * 64];
  __shared__ u16 lV[64 * 64];
  __shared__ u16 lP[64 * 72];
  const int t = threadIdx.x;
  const int lo = t & 15, hi = (t >> 4) & 3, w = t >> 6;
  const int swz = (blockIdx.x & 7) * 256 + (blockIdx.x >> 3);
  const int qt = swz & 15, bh = swz >> 4;
  const int b = bh >> 4, h = bh & 15;
  const int q0 = qt * 64;
  const u16* Qb = qkv + (size_t)b * 1024 * 3072 + h * 64;
  const u16* Kb = Qb + 1024;
  const u16* Vt = vT + (size_t)bh * 64 * 1024;

  bf16x8 qf[2];
  {
    const size_t q = q0 + w * 16 + lo;
    qf[0] = *(const bf16x8*)(Qb + q * 3072 + hi * 8);
    qf[1] = *(const bf16x8*)(Qb + q * 3072 + 32 + hi * 8);
  }
  f32x4 oacc[4];
  #pragma unroll
  for (int i = 0; i < 4; ++i) oacc[i] = (f32x4){0.f, 0.f, 0.f, 0.f};
  float m = -1e30f, lsum = 0.f;
  const int srow = t >> 3;
  const int sc = (t & 7) ^ (srow & 7);
  const int xr = lo & 7;
  const float SC = 0.125f * 1.44269504f;

  for (int kv0 = 0; kv0 < 1024; kv0 += 64) {
    __syncthreads();
    #pragma unroll
    for (int j = 0; j < 2; ++j) {
      const int r64 = j * 32 + srow;
      gld16(Kb + (size_t)(kv0 + r64) * 3072 + sc * 8, &lK[(j * 256 + t) * 8]);
      gld16(Vt + (size_t)r64 * 1024 + kv0 + sc * 8, &lV[(j * 256 + t) * 8]);
    }
    __syncthreads();

    f32x4 s[4];
    #pragma unroll
    for (int i = 0; i < 4; ++i) s[i] = (f32x4){0.f, 0.f, 0.f, 0.f};
    #pragma unroll
    for (int kk = 0; kk < 2; ++kk) {
      #pragma unroll
      for (int mi = 0; mi < 4; ++mi) {
        const bf16x8 kf = *(const bf16x8*)&lK[(mi * 16 + lo) * 64 + (((kk << 2) + hi) ^ xr) * 8];
        s[mi] = __builtin_amdgcn_mfma_f32_16x16x32_bf16(kf, qf[kk], s[mi], 0, 0, 0);
      }
    }
    float sv[16];
    float tmax = -1e30f;
    #pragma unroll
    for (int mi = 0; mi < 4; ++mi)
      #pragma unroll
      for (int r = 0; r < 4; ++r) {
        const float xx = s[mi][r] * SC;
        sv[mi * 4 + r] = xx;
        tmax = fmaxf(tmax, xx);
      }
    tmax = fmaxf(tmax, __shfl_xor(tmax, 16));
    tmax = fmaxf(tmax, __shfl_xor(tmax, 32));
    if (__any(tmax > m + 11.5f)) {
      const float mnew = fmaxf(m, tmax);
      const float alpha = exp2f(m - mnew);
      m = mnew;
      lsum *= alpha;
      float ar[4];
      #pragma unroll
      for (int r = 0; r < 4; ++r) ar[r] = __shfl(alpha, hi * 4 + r);
      #pragma unroll
      for (int ni = 0; ni < 4; ++ni)
        #pragma unroll
        for (int r = 0; r < 4; ++r) oacc[ni][r] *= ar[r];
    }
    float p[16], ts = 0.f;
    #pragma unroll
    for (int i = 0; i < 16; ++i) { p[i] = exp2f(sv[i] - m); ts += p[i]; }
    ts += __shfl_xor(ts, 16);
    ts += __shfl_xor(ts, 32);
    lsum += ts;
    #pragma unroll
    for (int mi = 0; mi < 4; ++mi) {
      uint2 pk;
      pk.x = f2bf(p[mi * 4 + 0]) | ((unsigned)f2bf(p[mi * 4 + 1]) << 16);
      pk.y = f2bf(p[mi * 4 + 2]) | ((unsigned)f2bf(p[mi * 4 + 3]) << 16);
      *(uint2*)&lP[(w * 16 + lo) * 72 + mi * 16 + hi * 4] = pk;
    }
    asm volatile("s_waitcnt lgkmcnt(0)" ::: "memory");
    #pragma unroll
    for (int kk = 0; kk < 2; ++kk) {
      const bf16x8 pf = *(const bf16x8*)&lP[(w * 16 + lo) * 72 + kk * 32 + hi * 8];
      #pragma unroll
      for (int ni = 0; ni < 4; ++ni) {
        const bf16x8 vf = *(const bf16x8*)&lV[(ni * 16 + lo) * 64 + (((kk << 2) + hi) ^ xr) * 8];
        oacc[ni] = __builtin_amdgcn_mfma_f32_16x16x32_bf16(pf, vf, oacc[ni], 0, 0, 0);
      }
    }
  }
  float lr[4];
  #pragma unroll
  for (int r = 0; r < 4; ++r) lr[r] = 1.f / __shfl(lsum, hi * 4 + r);
  #pragma unroll
  for (int ni = 0; ni < 4; ++ni) {
    const int d = ni * 16 + lo;
    #pragma unroll
    for (int r = 0; r < 4; ++r) {
      const int n = q0 + w * 16 + hi * 4 + r;
      o[((size_t)(b * 1024 + n) * 16 + h) * 64 + d] = f2bf(oacc[ni][r] * lr[r]);
    }
  }
}

// ---------- launch ----------
extern "C" void kernel_launch(void* const* d_in, const int* in_sizes, int n_in,
                              void* d_out, int out_size, void* d_ws, size_t ws_size,
                              hipStream_t stream) {
  const float* x      = (const float*)d_in[0];
  const float* qkv_w  = (const float*)d_in[1];
  const float* qkv_b  = (const float*)d_in[2];
  const float* proj_w = (const float*)d_in[3];
  const float* proj_b = (const float*)d_in[4];
  const float* fc1_w  = (const float*)d_in[5];
  const float* fc1_b  = (const float*)d_in[6];
  const float* fc2_w  = (const float*)d_in[7];
  const float* fc2_b  = (const float*)d_in[8];
  const float* ln1_g  = (const float*)d_in[9];
  const float* ln1_b  = (const float*)d_in[10];
  const float* ln2_g  = (const float*)d_in[11];
  const float* ln2_b  = (const float*)d_in[12];
  float* out = (float*)d_out;
  char* ws = (char*)d_ws;
  u16* wqkvT = (u16*)(ws);              // [3072][1024]  6,291,456
  u16* wprojT = (u16*)(ws + 6291456);   // [1024][1024]  2,097,152
  u16* wfc1T = (u16*)(ws + 8388608);    // [4096][1024]  8,388,608
  u16* wfc2T = (u16*)(ws + 16777216);   // [1024][4096]  8,388,608
  u16* hbuf  = (u16*)(ws + 25165824);   // [8192][1024] 16,777,216
  u16* qkvo  = (u16*)(ws + 41943040);   // [8192][3072] 50,331,648
  u16* vT    = (u16*)(ws + 92274688);   // [128][64][1024] 16,777,216
  u16* fc1o  = qkvo;                    // [8192][4096] overlays qkv+vT (both dead)

  prep_k<<<20480, 256, 0, stream>>>(qkv_w, proj_w, fc1_w, fc2_w,
                                    wqkvT, wprojT, wfc1T, wfc2T,
                                    x, ln1_g, ln1_b, hbuf);
  gemm_k<3, 4><<<384, 512, 0, stream>>>(hbuf, wqkvT, qkv_b, qkvo, nullptr, nullptr, vT, 8192, 3072, 1024);
  attn_k<<<2048, 256, 0, stream>>>(qkvo, vT, hbuf);
  gemm_k<2, 2><<<256, 512, 0, stream>>>(hbuf, wprojT, proj_b, nullptr, out, x, nullptr, 8192, 1024, 1024);
  ln_cast_k<<<8192, 256, 0, stream>>>(out, ln2_g, ln2_b, hbuf);
  gemm_k<1, 4><<<512, 512, 0, stream>>>(hbuf, wfc1T, fc1_b, fc1o, nullptr, nullptr, nullptr, 8192, 4096, 1024);
  gemm_k<2, 2><<<256, 512, 0, stream>>>(fc1o, wfc2T, fc2_b, nullptr, out, out, nullptr, 8192, 1024, 4096);
}